// Round 8
// baseline (133.848 us; speedup 1.0000x reference)
//
#include <hip/hip_runtime.h>

// StericClashConstraint: N=16384 pts [N,3] fp32.
// out[0..3N-1] = pos passthrough; out[3N] = mean(max(1-dist,0), diag=0) * 0.02
//
// Round 8: ALGORITHMIC. A violating pair needs dist<1 => |dx|<1; x~N(0,5) so
// only ~11% of pairs can violate. Counting-sort points by x (bins 1/32 wide),
// then each lane scans its contiguous sorted j-window (j>i) with monotone
// exit at dx >= 1.0625 (margin covers within-bin disorder: bin floors are
// nondecreasing, so after dx>=1.0625 all later x_j > x_i+1). ~18x less pair
// work than R6's brute force; j-loads are coalesced 16B/lane from L2.
// Pairs counted once (j>i in sorted index), doubled at the end; diagonal
// excluded structurally (d>=1). Inactive lanes have d2>dx^2>1 -> auto-zero.

constexpr int   N        = 16384;
constexpr int   NBINS    = 2048;      // x in [-32,32), width 1/32
constexpr float BIN_LO   = -32.0f;
constexpr float BIN_INV  = 32.0f;
constexpr int   PAD      = 64;        // sentinel tail
constexpr int   IMAX     = N + PAD - 1;

constexpr int   PBLOCKS  = 2048;      // pair kernel blocks (8/CU)
constexpr int   WPB      = 4;         // waves/block
constexpr int   SLICES   = 32;        // d-slices per 64-i batch
constexpr int   DSLICE   = 64;        // d's per slice (last slice unbounded)
// batches = N/64 = 256 ; wave-tasks = 256*32 = 8192 = PBLOCKS*WPB  (exact)

// ws layout (bytes): [0]=acc f32, [4]=done u32, [64..64+8192)=hist u32[2048],
// [8320 ...)= sorted float4[N+PAD]  (total ~271.5 KB)

__global__ void prep_kernel(const float* __restrict__ pos, float* __restrict__ out,
                            unsigned int* __restrict__ hist, float4* __restrict__ srt) {
    const int t = blockIdx.x * blockDim.x + threadIdx.x;   // 0..16383
    if (t < (N * 3) / 4)
        reinterpret_cast<float4*>(out)[t] = reinterpret_cast<const float4*>(pos)[t];
    const float x = pos[3 * t];
    int bin = (int)floorf((x - BIN_LO) * BIN_INV);
    bin = min(max(bin, 0), NBINS - 1);
    atomicAdd(&hist[bin], 1u);
    if (t < PAD)                                            // sentinels: never violate
        srt[N + t] = make_float4(1.0e9f, 1.0e9f, 1.0e9f, 3.0e18f);
}

__global__ void __launch_bounds__(256) scan_kernel(unsigned int* __restrict__ hist) {
    // in-place exclusive prefix over 2048 bins; hist becomes scatter cursors
    __shared__ unsigned int sums[256];
    const int t = threadIdx.x;
    unsigned int v[8];
    unsigned int tot = 0;
    #pragma unroll
    for (int k = 0; k < 8; ++k) { v[k] = hist[t * 8 + k]; tot += v[k]; }
    sums[t] = tot;
    __syncthreads();
    for (int off = 1; off < 256; off <<= 1) {               // Hillis-Steele inclusive
        unsigned int add = (t >= off) ? sums[t - off] : 0u;
        __syncthreads();
        sums[t] += add;
        __syncthreads();
    }
    unsigned int run = sums[t] - tot;                       // exclusive base
    #pragma unroll
    for (int k = 0; k < 8; ++k) { hist[t * 8 + k] = run; run += v[k]; }
}

__global__ void scatter_kernel(const float* __restrict__ pos,
                               unsigned int* __restrict__ cursor,
                               float4* __restrict__ srt) {
    const int t = blockIdx.x * blockDim.x + threadIdx.x;    // 0..16383
    const float x = pos[3 * t], y = pos[3 * t + 1], z = pos[3 * t + 2];
    int bin = (int)floorf((x - BIN_LO) * BIN_INV);
    bin = min(max(bin, 0), NBINS - 1);
    const unsigned int dst = atomicAdd(&cursor[bin], 1u);
    srt[dst] = make_float4(x, y, z, fmaf(x, x, fmaf(y, y, z * z)));
}

__global__ void __launch_bounds__(256, 8)
pair_kernel(const float4* __restrict__ srt, float* __restrict__ out,
            float* __restrict__ acc, unsigned int* __restrict__ cnt) {
    __shared__ float wsum[WPB];
    const int lane  = threadIdx.x & 63;
    const int wv    = threadIdx.x >> 6;
    const int g     = blockIdx.x * WPB + wv;                // 0..8191
    const int batch = g >> 5;                               // /SLICES -> 0..255
    const int slice = g & (SLICES - 1);
    const int i     = (batch << 6) + lane;                  // this lane's sorted i

    const float4 pi = srt[i];
    const float xi = pi.x, yi = pi.y, zi = pi.z;

    int d = 1 + slice * DSLICE;
    const int dEnd = d + DSLICE;
    const bool last = (slice == SLICES - 1);                // unbounded tail slice

    float s = 0.0f;
    float4 pj = srt[min(i + d, IMAX)];
    while (true) {
        const float4 pn = srt[min(i + d + 1, IMAX)];        // prefetch next j
        const float dx = pj.x - xi;
        if (__ballot(dx < 1.0625f) == 0ull) break;          // monotone window exit
        const float dy = pj.y - yi;
        const float dz = pj.z - zi;
        const float d2 = fmaf(dx, dx, fmaf(dy, dy, dz * dz));
        if (__ballot(d2 < 1.0f)) {                          // rare
            if (d2 < 1.0f) s += 1.0f - __builtin_amdgcn_sqrtf(d2);
        }
        ++d;
        if (d >= dEnd && !last) break;
        pj = pn;
    }

    // reduce: wave shuffle -> LDS -> one atomic per block
    for (int off = 32; off > 0; off >>= 1) s += __shfl_down(s, off);
    if (lane == 0) wsum[wv] = s;
    __syncthreads();
    if (threadIdx.x == 0) {
        float bs = 0.0f;
        #pragma unroll
        for (int w = 0; w < WPB; ++w) bs += wsum[w];
        atomicAdd(acc, bs);
        __threadfence();
        const unsigned int done = atomicAdd(cnt, 1u);
        if (done == (unsigned int)(PBLOCKS - 1)) {          // last block finalizes
            __threadfence();
            const float total = atomicAdd(acc, 0.0f);       // device-coherent read
            const double mean = 2.0 * (double)total / ((double)N * (double)N);
            out[(size_t)N * 3] = (float)(mean * 0.02);
        }
    }
}

extern "C" void kernel_launch(void* const* d_in, const int* in_sizes, int n_in,
                              void* d_out, int out_size, void* d_ws, size_t ws_size,
                              hipStream_t stream) {
    const float* pos = (const float*)d_in[0];
    float* out = (float*)d_out;
    float*        acc  = (float*)d_ws;
    unsigned int* cnt  = (unsigned int*)d_ws + 1;
    unsigned int* hist = (unsigned int*)((char*)d_ws + 64);
    float4*       srt  = (float4*)((char*)d_ws + 8320);

    hipMemsetAsync(d_ws, 0, 64 + NBINS * 4, stream);        // acc, cnt, hist

    prep_kernel<<<N / 256, 256, 0, stream>>>(pos, out, hist, srt);
    scan_kernel<<<1, 256, 0, stream>>>(hist);
    scatter_kernel<<<N / 256, 256, 0, stream>>>(pos, hist, srt);
    pair_kernel<<<PBLOCKS, 256, 0, stream>>>(srt, out, acc, cnt);
}

// Round 9
// 125.619 us; speedup vs baseline: 1.0655x; 1.0655x over previous
//
#include <hip/hip_runtime.h>

// StericClashConstraint: N=16384 pts [N,3] fp32.
// out[0..3N-1] = pos passthrough; out[3N] = mean(max(1-dist,0), diag=0) * 0.02
//
// Round 9: x-sorted window prune (R8) with the latency bug fixed. R8's inner
// loop had a data-dependent ballot exit between the prefetch and its use, so
// every 64-pair iteration paid a serialized L2 round trip (66us). Now each
// lane's window end comes from the bin prefix table (e = cursor[bin+33] =>
// all later j have dx > 33/32 > 1), the wave-max makes the loop COUNTED, and
// groups of 4 j's are processed with unconditional 4-deep prefetch and
// branch-free accumulation: s += max(1-sqrt(d2), 0). Out-of-window pairs
// auto-zero, so no predicates at all. Pairs counted once (j>i sorted),
// doubled at the end; diagonal excluded structurally (d>=1).

constexpr int   N       = 16384;
constexpr int   NBINS   = 2048;      // x in [-32,32), width 1/32
constexpr float BIN_LO  = -32.0f;
constexpr float BIN_INV = 32.0f;
constexpr int   PAD     = 80;        // sentinel tail (clamped loads land here)
constexpr int   IMAX    = N + PAD - 1;
constexpr int   WPB     = 4;         // waves per block
constexpr int   PBLOCKS = 2048;
constexpr int   SLICES  = 32;        // d-slices per 64-i batch
constexpr int   BATCHES = N / 64;    // 256 ; tasks = 256*32 = 8192 = PBLOCKS*WPB

// ws layout (bytes): [0]=acc f32, [4]=done u32, [64..64+8192)=hist u32[2048],
// [8320 ...)= sorted float4[N+PAD]

__global__ void prep_kernel(const float* __restrict__ pos, float* __restrict__ out,
                            unsigned int* __restrict__ hist, float4* __restrict__ srt) {
    const int t = blockIdx.x * blockDim.x + threadIdx.x;   // 0..16383
    if (t < (N * 3) / 4)
        reinterpret_cast<float4*>(out)[t] = reinterpret_cast<const float4*>(pos)[t];
    const float x = pos[3 * t];
    int bin = (int)floorf((x - BIN_LO) * BIN_INV);
    bin = min(max(bin, 0), NBINS - 1);
    atomicAdd(&hist[bin], 1u);
    if (t < PAD)                                           // sentinels: huge, never count
        srt[N + t] = make_float4(1.0e9f, 1.0e9f, 1.0e9f, 3.0e18f);
}

__global__ void scan_kernel(unsigned int* __restrict__ hist) {
    // one wave, barrier-free: lane handles 32 consecutive bins
    const int lane = threadIdx.x;                          // 0..63
    unsigned int v[32], tot = 0;
    #pragma unroll
    for (int k = 0; k < 32; ++k) { v[k] = hist[lane * 32 + k]; tot += v[k]; }
    unsigned int run = tot;                                // inclusive wave scan
    #pragma unroll
    for (int off = 1; off < 64; off <<= 1) {
        const unsigned int u = __shfl_up(run, off);
        if (lane >= off) run += u;
    }
    unsigned int excl = run - tot;                         // exclusive base
    #pragma unroll
    for (int k = 0; k < 32; ++k) { hist[lane * 32 + k] = excl; excl += v[k]; }
}

__global__ void scatter_kernel(const float* __restrict__ pos,
                               unsigned int* __restrict__ cursor,
                               float4* __restrict__ srt) {
    const int t = blockIdx.x * blockDim.x + threadIdx.x;   // 0..16383
    const float x = pos[3 * t], y = pos[3 * t + 1], z = pos[3 * t + 2];
    int bin = (int)floorf((x - BIN_LO) * BIN_INV);
    bin = min(max(bin, 0), NBINS - 1);
    const unsigned int dst = atomicAdd(&cursor[bin], 1u);
    srt[dst] = make_float4(x, y, z, 0.0f);
    // after this kernel, cursor[b] == start index of bin b+1 (window-end table)
}

__device__ __forceinline__ float pair_term(const float4 pj, float xi, float yi, float zi) {
    const float dx = pj.x - xi, dy = pj.y - yi, dz = pj.z - zi;
    const float d2 = fmaf(dx, dx, fmaf(dy, dy, dz * dz));
    return fmaxf(1.0f - __builtin_amdgcn_sqrtf(d2), 0.0f); // auto-zero when far
}

__global__ void __launch_bounds__(256, 4)
pair_kernel(const float4* __restrict__ srt, const unsigned int* __restrict__ binEnd,
            float* __restrict__ out, float* __restrict__ acc,
            unsigned int* __restrict__ cnt) {
    __shared__ float wsum[WPB];
    const int lane  = threadIdx.x & 63;
    const int wv    = threadIdx.x >> 6;
    const int g     = blockIdx.x * WPB + wv;               // 0..8191
    const int batch = g & (BATCHES - 1);                   // slice-tier mapping:
    const int slice = g >> 8;                              // early blocks = busy tiers
    const int i     = (batch << 6) + lane;

    const float4 pi = srt[i];
    const float xi = pi.x, yi = pi.y, zi = pi.z;

    // window end from bin table: j >= e  =>  x_j - x_i > 33/32 > 1
    int bin = (int)floorf((xi - BIN_LO) * BIN_INV);
    bin = min(max(bin, 0), NBINS - 1);
    const int e   = (int)binEnd[min(bin + 33, NBINS - 1)];
    int dmax = e - i;                                      // >= 1 always
    #pragma unroll
    for (int off = 32; off > 0; off >>= 1) dmax = max(dmax, __shfl_xor(dmax, off));
    const int dcap = dmax - 1;                             // largest d any lane needs
    const int dlo  = 1 + slice * 64;

    float s = 0.0f;
    if (dlo <= dcap) {
        const int dhi    = (slice == SLICES - 1) ? dcap : min(dcap, dlo + 63);
        const int groups = (dhi - dlo + 4) >> 2;           // overshoot auto-zeros
        int jb = i + dlo;
        float4 c0 = srt[min(jb + 0, IMAX)];
        float4 c1 = srt[min(jb + 1, IMAX)];
        float4 c2 = srt[min(jb + 2, IMAX)];
        float4 c3 = srt[min(jb + 3, IMAX)];
        for (int gi = 0; gi < groups; ++gi) {
            const float4 n0 = srt[min(jb + 4, IMAX)];      // 4 loads in flight
            const float4 n1 = srt[min(jb + 5, IMAX)];
            const float4 n2 = srt[min(jb + 6, IMAX)];
            const float4 n3 = srt[min(jb + 7, IMAX)];
            s += pair_term(c0, xi, yi, zi);
            s += pair_term(c1, xi, yi, zi);
            s += pair_term(c2, xi, yi, zi);
            s += pair_term(c3, xi, yi, zi);
            c0 = n0; c1 = n1; c2 = n2; c3 = n3;
            jb += 4;
        }
    }

    // reduce: wave shuffle -> LDS -> one atomic per block
    for (int off = 32; off > 0; off >>= 1) s += __shfl_down(s, off);
    if (lane == 0) wsum[wv] = s;
    __syncthreads();
    if (threadIdx.x == 0) {
        float bs = 0.0f;
        #pragma unroll
        for (int w = 0; w < WPB; ++w) bs += wsum[w];
        atomicAdd(acc, bs);
        __threadfence();
        const unsigned int done = atomicAdd(cnt, 1u);
        if (done == (unsigned int)(PBLOCKS - 1)) {         // last block finalizes
            __threadfence();
            const float total = atomicAdd(acc, 0.0f);      // device-coherent read
            const double mean = 2.0 * (double)total / ((double)N * (double)N);
            out[(size_t)N * 3] = (float)(mean * 0.02);
        }
    }
}

extern "C" void kernel_launch(void* const* d_in, const int* in_sizes, int n_in,
                              void* d_out, int out_size, void* d_ws, size_t ws_size,
                              hipStream_t stream) {
    const float* pos = (const float*)d_in[0];
    float* out = (float*)d_out;
    float*        acc  = (float*)d_ws;
    unsigned int* cnt  = (unsigned int*)d_ws + 1;
    unsigned int* hist = (unsigned int*)((char*)d_ws + 64);
    float4*       srt  = (float4*)((char*)d_ws + 8320);

    hipMemsetAsync(d_ws, 0, 64 + NBINS * 4, stream);       // acc, cnt, hist

    prep_kernel<<<N / 256, 256, 0, stream>>>(pos, out, hist, srt);
    scan_kernel<<<1, 64, 0, stream>>>(hist);
    scatter_kernel<<<N / 256, 256, 0, stream>>>(pos, hist, srt);
    pair_kernel<<<PBLOCKS, 256, 0, stream>>>(srt, hist, out, acc, cnt);
}